// Round 13
// baseline (1117.650 us; speedup 1.0000x reference)
//
#include <hip/hip_runtime.h>

#define NN   30000
#define NE   480000
#define NR   7
#define NSEG (NN*NR)
#define DH   512
#define DIN  21
#define EPSB 1e-5f
#define BK   32
#define KSEG 3584          // 7*512 gathered columns (self handled from hbf)

typedef __attribute__((ext_vector_type(8))) short bf16x8;
typedef __attribute__((ext_vector_type(8))) unsigned short u16x8;
typedef __attribute__((ext_vector_type(4))) float f32x4;
typedef unsigned short ushortT;

static inline size_t align256(size_t x){ return (x + 255) & ~(size_t)255; }

__device__ inline float bf2f(ushortT u){
    unsigned int i = ((unsigned int)u) << 16; float f; __builtin_memcpy(&f, &i, 4); return f;
}
__device__ inline ushortT f2bf(float f){
    unsigned int i; __builtin_memcpy(&i, &f, 4);
    unsigned int r = i + 0x7FFFu + ((i >> 16) & 1u);
    return (ushortT)(r >> 16);
}

__device__ inline void load_lds16(const ushortT* g, ushortT* l){
    __builtin_amdgcn_global_load_lds((const __attribute__((address_space(1))) unsigned int*)g,
                                     (__attribute__((address_space(3))) unsigned int*)l,
                                     16, 0, 0);
}

// ---------------- CSR build (counting sort by seg = dst*7+rel) ----------------

__global__ void hist_k(const int* __restrict__ dst, const int* __restrict__ rel,
                       int* __restrict__ counts){
    int e = blockIdx.x*256 + threadIdx.x;
    if (e < NE) atomicAdd(&counts[dst[e]*NR + rel[e]], 1);
}

__global__ void scan1_k(const int* __restrict__ counts, int* __restrict__ bsum){
    __shared__ int sd[256];
    int t = threadIdx.x;
    int base = blockIdx.x*1024 + t*4;
    int s = 0;
#pragma unroll
    for (int i = 0; i < 4; i++){ int idx = base + i; if (idx < NSEG) s += counts[idx]; }
    sd[t] = s; __syncthreads();
    for (int off = 128; off > 0; off >>= 1){
        if (t < off) sd[t] += sd[t+off];
        __syncthreads();
    }
    if (t == 0) bsum[blockIdx.x] = sd[0];
}

__global__ void scan2_k(int* __restrict__ bsum, int nb, int* __restrict__ seg_start){
    __shared__ int sd[256];
    int t = threadIdx.x;
    int v = (t < nb) ? bsum[t] : 0;
    sd[t] = v; __syncthreads();
    for (int off = 1; off < 256; off <<= 1){
        int x = sd[t];
        if (t >= off) x += sd[t-off];
        __syncthreads();
        sd[t] = x; __syncthreads();
    }
    if (t < nb) bsum[t] = (t == 0) ? 0 : sd[t-1];
    if (t == 0) seg_start[NSEG] = NE;
}

__global__ void scan3_k(const int* __restrict__ counts, const int* __restrict__ bsum,
                        int* __restrict__ seg_start){
    __shared__ int sd[256];
    int t = threadIdx.x;
    int base = blockIdx.x*1024 + t*4;
    int v[4]; int s = 0;
#pragma unroll
    for (int i = 0; i < 4; i++){ int idx = base + i; v[i] = (idx < NSEG) ? counts[idx] : 0; s += v[i]; }
    sd[t] = s; __syncthreads();
    for (int off = 1; off < 256; off <<= 1){
        int x = sd[t];
        if (t >= off) x += sd[t-off];
        __syncthreads();
        sd[t] = x; __syncthreads();
    }
    int excl = sd[t] - s + bsum[blockIdx.x];
#pragma unroll
    for (int i = 0; i < 4; i++){
        int idx = base + i;
        if (idx < NSEG){ seg_start[idx] = excl; excl += v[i]; }
    }
}

__global__ void scatter_k(const int* __restrict__ src, const int* __restrict__ dst,
                          const int* __restrict__ rel, const int* __restrict__ seg_start,
                          int* __restrict__ cursor, int* __restrict__ src_sorted){
    int e = blockIdx.x*256 + threadIdx.x;
    if (e < NE){
        int s = dst[e]*NR + rel[e];
        int pos = seg_start[s] + atomicAdd(&cursor[s], 1);
        src_sorted[pos] = src[e];
    }
}

// ---------------- layer 0: segment sum d=21, Kp=192 (147 upd | 21 self | 24 pad) ----------------

__global__ void segsum21b_k(const float* __restrict__ x0,
                            const int* __restrict__ seg_start, const int* __restrict__ src_sorted,
                            ushortT* __restrict__ Acat){
    int n = blockIdx.x;
    int t = threadIdx.x;   // 64
    ushortT* arow = Acat + (long)n*192;
    if (t < DIN){
        int sb = n*NR;
        int e0 = seg_start[sb];
#pragma unroll
        for (int r = 0; r < NR; r++){
            int e1 = seg_start[sb + r + 1];
            float a = 0.f;
            for (int e = e0; e < e1; e++) a += x0[(long)src_sorted[e]*DIN + t];
            e0 = e1;
            arow[r*DIN + t] = f2bf(a);
        }
        arow[7*DIN + t] = f2bf(x0[(long)n*DIN + t]);
    }
    if (t >= 40) arow[168 + (t - 40)] = 0;   // zero pad cols 168..191
}

// ---------------- segsum (layers 1,2): one WAVE per node → Acat[*,3584], grid-stride --------

__device__ inline void segsum_body(const ushortT* __restrict__ hbf,
                                   const int* __restrict__ seg_start,
                                   const int* __restrict__ src_sorted,
                                   ushortT* __restrict__ Acat,
                                   int wid, int c0, int lane){
    const int n = c0 + wid;
    const int co = lane*8;

    int sb[8];
#pragma unroll
    for (int i = 0; i < 8; i++) sb[i] = seg_start[n*NR + i];

    ushortT* arow = Acat + (long)wid*KSEG + co;
#pragma unroll
    for (int r = 0; r < NR; r++){
        float a[8];
#pragma unroll
        for (int j = 0; j < 8; j++) a[j] = 0.f;
        int e = sb[r], e1 = sb[r+1];
        for (; e + 3 < e1; e += 4){
            u16x8 v0 = *reinterpret_cast<const u16x8*>(hbf + (long)src_sorted[e  ]*DH + co);
            u16x8 v1 = *reinterpret_cast<const u16x8*>(hbf + (long)src_sorted[e+1]*DH + co);
            u16x8 v2 = *reinterpret_cast<const u16x8*>(hbf + (long)src_sorted[e+2]*DH + co);
            u16x8 v3 = *reinterpret_cast<const u16x8*>(hbf + (long)src_sorted[e+3]*DH + co);
#pragma unroll
            for (int j = 0; j < 8; j++)
                a[j] += (bf2f((ushortT)v0[j]) + bf2f((ushortT)v1[j]))
                      + (bf2f((ushortT)v2[j]) + bf2f((ushortT)v3[j]));
        }
        for (; e < e1; e++){
            u16x8 v = *reinterpret_cast<const u16x8*>(hbf + (long)src_sorted[e]*DH + co);
#pragma unroll
            for (int j = 0; j < 8; j++) a[j] += bf2f((ushortT)v[j]);
        }
        u16x8 o;
#pragma unroll
        for (int j = 0; j < 8; j++) o[j] = f2bf(a[j]);
        *reinterpret_cast<u16x8*>(arow + r*DH) = o;
    }
}

__global__ __launch_bounds__(256)
void segsum_wave_k(const ushortT* __restrict__ hbf,
                   const int* __restrict__ seg_start, const int* __restrict__ src_sorted,
                   ushortT* __restrict__ Acat, int c0, int cn){
    const int lane = threadIdx.x & 63;
    const int gwave = (blockIdx.x*256 + threadIdx.x) >> 6;
    const int nwaves = (gridDim.x*256) >> 6;
    for (int wid = gwave; wid < cn; wid += nwaves)
        segsum_body(hbf, seg_start, src_sorted, Acat, wid, c0, lane);
}

// ---------------- weight concat + bf16 convert: Wcat[512][Kp] ----------------

__global__ void convw_k(const float* __restrict__ lw, const float* __restrict__ sw,
                        int d, int Kp, ushortT* __restrict__ Wc){
    int i = blockIdx.x*256 + threadIdx.x;
    if (i < DH*Kp){
        int n = i / Kp, k = i % Kp;
        float v;
        if (k < 7*d)      v = lw[(long)n*7*d + k];
        else if (k < 8*d) v = sw[(long)n*d + (k - 7*d)];
        else              v = 0.f;
        Wc[i] = f2bf(v);
    }
}

// ---------------- MFMA GEMM: BM=256 x BN=128, 512 thr, 8 waves (4Mx2N of 64x64) -------------
// T2 swizzle both-sides (zero bank conflict, verified R12), 3-buf LDS (72 KB -> 2 blocks/CU),
// counted vmcnt(3) + raw barrier, bijective XCD panel-group swizzle (4 col-tiles co-XCD).
// A-tiles kt<ntA from A (lda); kt>=ntA from hbase (self-loop, ld=512). bf16 C + fused stats.

__global__ __launch_bounds__(512)
void gemm_mfma_k(const ushortT* __restrict__ A, int lda, int ntA,
                 const ushortT* __restrict__ hbase, int M,
                 const ushortT* __restrict__ W, int ldw,
                 const float* __restrict__ b1, const float* __restrict__ b2,
                 ushortT* __restrict__ C, int nt, float* __restrict__ sums){
    __shared__ ushortT As[3][256*BK];   // 48 KB
    __shared__ ushortT Bs[3][128*BK];   // 24 KB
    const int t = threadIdx.x;

    // bijective XCD swizzle (m204): panel = l>>2, col-tile = l&3
    const int nwg = gridDim.x;
    int q = nwg >> 3, rmd = nwg & 7;
    int xcd = blockIdx.x & 7, slot = blockIdx.x >> 3;
    int l = xcd*q + min(xcd, rmd) + slot;
    const int bm = (l >> 2)*256;
    const int bn = (l & 3)*128;

    // staging: A tile 1024 units (2/thread: f0=t, f1=t+512), B tile 512 units (1/thread)
    const int f0 = t, f1 = t + 512;
    const int ac0 = ((f0 & 3) ^ ((f0 >> 3) & 3))*8;   // T2 source swizzle
    const int ac1 = ((f1 & 3) ^ ((f1 >> 3) & 3))*8;
    const int ar0 = min(bm + (f0 >> 2), M-1);
    const int ar1 = min(bm + (f1 >> 2), M-1);
    const int brw = bn + (f0 >> 2);                    // 0..127

    f32x4 acc[4][4];
#pragma unroll
    for (int m = 0; m < 4; m++)
#pragma unroll
        for (int n = 0; n < 4; n++) acc[m][n] = (f32x4){0.f,0.f,0.f,0.f};

    const int w = t >> 6;
    const int lane = t & 63;
    const int wm = w >> 1, wn = w & 1;     // 4 x 2 wave grid of 64x64
    const int r = lane & 15, hi = lane >> 4;
    const int ko = (hi ^ ((r >> 1) & 3))*8;            // T2 read swizzle

    auto stage = [&](int kt, int b){
        const ushortT* p0;
        const ushortT* p1;
        if (kt < ntA){
            p0 = A + (long)ar0*lda + kt*BK + ac0;
            p1 = A + (long)ar1*lda + kt*BK + ac1;
        } else {
            int k0 = (kt - ntA)*BK;
            p0 = hbase + (long)ar0*DH + k0 + ac0;
            p1 = hbase + (long)ar1*DH + k0 + ac1;
        }
        load_lds16(p0, &As[b][t*8]);
        load_lds16(p1, &As[b][(t + 512)*8]);
        load_lds16(W + (long)brw*ldw + kt*BK + ac0, &Bs[b][t*8]);
    };

    stage(0, 0);
    if (nt > 1) stage(1, 1);

    for (int kt = 0; kt < nt; ++kt){
        if (kt + 1 < nt) asm volatile("s_waitcnt vmcnt(3)" ::: "memory");
        else             asm volatile("s_waitcnt vmcnt(0)" ::: "memory");
        __builtin_amdgcn_s_barrier();
        __builtin_amdgcn_sched_barrier(0);
        if (kt + 2 < nt) stage(kt + 2, (kt + 2) % 3);
        const int buf = kt % 3;
        bf16x8 af[4], bfr[4];
#pragma unroll
        for (int m = 0; m < 4; m++)
            af[m] = *reinterpret_cast<const bf16x8*>(&As[buf][(wm*64 + m*16 + r)*BK + ko]);
#pragma unroll
        for (int n = 0; n < 4; n++)
            bfr[n] = *reinterpret_cast<const bf16x8*>(&Bs[buf][(wn*64 + n*16 + r)*BK + ko]);
#pragma unroll
        for (int m = 0; m < 4; m++)
#pragma unroll
            for (int n = 0; n < 4; n++)
                acc[m][n] = __builtin_amdgcn_mfma_f32_16x16x32_bf16(af[m], bfr[n], acc[m][n], 0, 0, 0);
    }

    // epilogue: bias + bf16 store + fused column stats (on rounded values)
#pragma unroll
    for (int n = 0; n < 4; n++){
        int col = bn + wn*64 + n*16 + r;
        float bb = b1[col] + b2[col];
        float s = 0.f, s2 = 0.f;
#pragma unroll
        for (int m = 0; m < 4; m++){
            int row = bm + wm*64 + m*16 + hi*4;
#pragma unroll
            for (int q2 = 0; q2 < 4; q2++){
                if (row + q2 < M){
                    ushortT u = f2bf(acc[m][n][q2] + bb);
                    C[(long)(row + q2)*DH + col] = u;
                    float vr = bf2f(u);
                    s += vr; s2 = fmaf(vr, vr, s2);
                }
            }
        }
        s  += __shfl_xor(s, 16);  s  += __shfl_xor(s, 32);
        s2 += __shfl_xor(s2, 16); s2 += __shfl_xor(s2, 32);
        if (hi == 0){
            atomicAdd(&sums[col], s);
            atomicAdd(&sums[DH + col], s2);
        }
    }
}

// ---------------- BatchNorm passes (bf16 buffer) ----------------

__global__ void finalize_k(const float* __restrict__ sums, const float* __restrict__ g,
                           const float* __restrict__ b, float* __restrict__ ac){
    int c = blockIdx.x*256 + threadIdx.x;
    if (c < DH){
        float mu  = sums[c] * (1.f/NN);
        float var = sums[DH + c] * (1.f/NN) - mu*mu;
        var = fmaxf(var, 0.f);
        float a = g[c] * rsqrtf(var + EPSB);
        ac[c]      = a;
        ac[DH + c] = fmaf(-mu, a, b[c]);
    }
}

__global__ void bnrelu_k(ushortT* __restrict__ buf, int M, const float* __restrict__ ac,
                         float* __restrict__ sums2){
    int col = blockIdx.x*256 + threadIdx.x;
    int r0 = blockIdx.y*128;
    int r1 = min(r0 + 128, M);
    float a = ac[col], c = ac[DH + col];
    float s = 0.f, s2 = 0.f;
    for (int r = r0; r < r1; r++){
        long idx = (long)r*DH + col;
        float y = fmaxf(fmaf(a, bf2f(buf[idx]), c), 0.f);
        ushortT u = f2bf(y);
        buf[idx] = u;
        float yr = bf2f(u);
        s += yr; s2 = fmaf(yr, yr, s2);
    }
    atomicAdd(&sums2[col], s);
    atomicAdd(&sums2[DH + col], s2);
}

__global__ void bn2write_k(const ushortT* __restrict__ buf, const float* __restrict__ ac,
                           float* __restrict__ out, ushortT* __restrict__ hbf, int layer){
    long i = (long)blockIdx.x*256 + threadIdx.x;
    if (i < (long)NN*DH){
        int r = (int)(i >> 9);
        int c = (int)(i & 511);
        float h = fmaf(ac[c], bf2f(buf[i]), ac[DH + c]);
        out[(long)r*(3*DH) + layer*DH + c] = h;
        hbf[i] = f2bf(h);
    }
}

// ---------------- driver ----------------

extern "C" void kernel_launch(void* const* d_in, const int* in_sizes, int n_in,
                              void* d_out, int out_size, void* d_ws, size_t ws_size,
                              hipStream_t stream){
    const float* x0  = (const float*)d_in[0];
    const int*   src = (const int*)d_in[1];
    const int*   dst = (const int*)d_in[2];
    const int*   rel = (const int*)d_in[3];
    const float* lin_w[3]  = {(const float*)d_in[4],  (const float*)d_in[12], (const float*)d_in[20]};
    const float* self_w[3] = {(const float*)d_in[5],  (const float*)d_in[13], (const float*)d_in[21]};
    const float* lin_b[3]  = {(const float*)d_in[6],  (const float*)d_in[14], (const float*)d_in[22]};
    const float* self_b[3] = {(const float*)d_in[7],  (const float*)d_in[15], (const float*)d_in[23]};
    const float* bn1_g[3]  = {(const float*)d_in[8],  (const float*)d_in[16], (const float*)d_in[24]};
    const float* bn1_b[3]  = {(const float*)d_in[9],  (const float*)d_in[17], (const float*)d_in[25]};
    const float* bn2_g[3]  = {(const float*)d_in[10], (const float*)d_in[18], (const float*)d_in[26]};
    const float* bn2_b[3]  = {(const float*)d_in[11], (const float*)d_in[19], (const float*)d_in[27]};

    char* ws = (char*)d_ws;
    size_t off = 0;
    auto alloc = [&](size_t bytes)->char*{ char* p = ws + off; off = align256(off + bytes); return p; };

    int*     seg_start  = (int*)alloc((size_t)(NSEG+1)*4);
    int*     bsum       = (int*)alloc(1024*4);
    int*     src_sorted = (int*)alloc((size_t)NE*4);
    float*   stats      = (float*)alloc((size_t)8*DH*4);
    float*   sums1 = stats;            float* sums2 = stats + 2*DH;
    float*   ac1   = stats + 4*DH;     float* ac2   = stats + 6*DH;
    ushortT* outbuf = (ushortT*)alloc((size_t)NN*DH*2);
    ushortT* hbf    = (ushortT*)alloc((size_t)NN*DH*2);
    ushortT* Wcat   = (ushortT*)alloc((size_t)DH*4096*2);

    // Acat takes the remainder. counts/cursor (CSR build) and Acat0 (layer 0) are
    // ALIASED into the Acat region: both are dead before the first layer-1 segsum write.
    size_t remain = (ws_size > off) ? (ws_size - off) : 0;
    ushortT* Acat   = (ushortT*)(ws + off);
    int*     counts = (int*)Acat;
    int*     cursor = counts + NSEG;
    ushortT* Acat0  = (ushortT*)(cursor + NSEG);

    long max_nodes = (long)(remain / ((size_t)KSEG*2));
    int chunk = (int)((max_nodes > NN) ? NN : max_nodes);
    chunk &= ~255;
    if (chunk < 256) chunk = 256;

    // CSR build (graph is layer-invariant)
    hipMemsetAsync(counts, 0, (size_t)NSEG*4, stream);
    hipMemsetAsync(cursor, 0, (size_t)NSEG*4, stream);
    hist_k<<<(NE+255)/256, 256, 0, stream>>>(dst, rel, counts);
    int nb = (NSEG + 1023)/1024;
    scan1_k<<<nb, 256, 0, stream>>>(counts, bsum);
    scan2_k<<<1, 256, 0, stream>>>(bsum, nb, seg_start);
    scan3_k<<<nb, 256, 0, stream>>>(counts, bsum, seg_start);
    scatter_k<<<(NE+255)/256, 256, 0, stream>>>(src, dst, rel, seg_start, cursor, src_sorted);

    for (int layer = 0; layer < 3; layer++){
        int d  = (layer == 0) ? DIN : DH;
        int Kp = (layer == 0) ? 192 : 8*DH;
        convw_k<<<(DH*Kp + 255)/256, 256, 0, stream>>>(lin_w[layer], self_w[layer], d, Kp, Wcat);
        hipMemsetAsync(stats, 0, (size_t)4*DH*4, stream);   // sums1 + sums2

        if (layer == 0){
            segsum21b_k<<<NN, 64, 0, stream>>>(x0, seg_start, src_sorted, Acat0);
            gemm_mfma_k<<<((NN + 255)/256)*4, 512, 0, stream>>>(
                Acat0, 192, 6, Acat0, NN, Wcat, 192,
                lin_b[layer], self_b[layer], outbuf, 6, sums1);
        } else {
            for (int c0 = 0; c0 < NN; c0 += chunk){
                int cn = (NN - c0 < chunk) ? (NN - c0) : chunk;
                int sgrid = (cn + 3)/4; if (sgrid > 2048) sgrid = 2048;
                segsum_wave_k<<<sgrid, 256, 0, stream>>>(
                    hbf, seg_start, src_sorted, Acat, c0, cn);
                gemm_mfma_k<<<((cn + 255)/256)*4, 512, 0, stream>>>(
                    Acat, KSEG, 112, hbf + (long)c0*DH, cn, Wcat, 4096,
                    lin_b[layer], self_b[layer],
                    outbuf + (long)c0*DH, 128, sums1);
            }
        }

        finalize_k<<<2, 256, 0, stream>>>(sums1, bn1_g[layer], bn1_b[layer], ac1);
        bnrelu_k<<<dim3(2, (NN+127)/128), 256, 0, stream>>>(outbuf, NN, ac1, sums2);
        finalize_k<<<2, 256, 0, stream>>>(sums2, bn2_g[layer], bn2_b[layer], ac2);
        bn2write_k<<<((long)NN*DH + 255)/256, 256, 0, stream>>>(outbuf, ac2, (float*)d_out, hbf, layer);
    }
}

// Round 14
// 985.171 us; speedup vs baseline: 1.1345x; 1.1345x over previous
//
#include <hip/hip_runtime.h>

#define NN   30000
#define NE   480000
#define NR   7
#define NSEG (NN*NR)
#define DH   512
#define DIN  21
#define EPSB 1e-5f
#define BK   32
#define KSEG 3584          // 7*512 gathered columns (self handled from hbf)
#define CHMAX 15360        // chunk rows (mult of 128), ~110 MB Acat -> L3-resident
#define MAXRIDER 768       // rider blocks per fused dispatch (grid-stride over nodes)

typedef __attribute__((ext_vector_type(8))) short bf16x8;
typedef __attribute__((ext_vector_type(8))) unsigned short u16x8;
typedef __attribute__((ext_vector_type(4))) float f32x4;
typedef unsigned short ushortT;

static inline size_t align256(size_t x){ return (x + 255) & ~(size_t)255; }

__device__ inline float bf2f(ushortT u){
    unsigned int i = ((unsigned int)u) << 16; float f; __builtin_memcpy(&f, &i, 4); return f;
}
__device__ inline ushortT f2bf(float f){
    unsigned int i; __builtin_memcpy(&i, &f, 4);
    unsigned int r = i + 0x7FFFu + ((i >> 16) & 1u);
    return (ushortT)(r >> 16);
}

__device__ inline void load_lds16(const ushortT* g, ushortT* l){
    __builtin_amdgcn_global_load_lds((const __attribute__((address_space(1))) unsigned int*)g,
                                     (__attribute__((address_space(3))) unsigned int*)l,
                                     16, 0, 0);
}

// ---------------- CSR build (counting sort by seg = dst*7+rel) ----------------

__global__ void hist_k(const int* __restrict__ dst, const int* __restrict__ rel,
                       int* __restrict__ counts){
    int e = blockIdx.x*256 + threadIdx.x;
    if (e < NE) atomicAdd(&counts[dst[e]*NR + rel[e]], 1);
}

__global__ void scan1_k(const int* __restrict__ counts, int* __restrict__ bsum){
    __shared__ int sd[256];
    int t = threadIdx.x;
    int base = blockIdx.x*1024 + t*4;
    int s = 0;
#pragma unroll
    for (int i = 0; i < 4; i++){ int idx = base + i; if (idx < NSEG) s += counts[idx]; }
    sd[t] = s; __syncthreads();
    for (int off = 128; off > 0; off >>= 1){
        if (t < off) sd[t] += sd[t+off];
        __syncthreads();
    }
    if (t == 0) bsum[blockIdx.x] = sd[0];
}

__global__ void scan2_k(int* __restrict__ bsum, int nb, int* __restrict__ seg_start){
    __shared__ int sd[256];
    int t = threadIdx.x;
    int v = (t < nb) ? bsum[t] : 0;
    sd[t] = v; __syncthreads();
    for (int off = 1; off < 256; off <<= 1){
        int x = sd[t];
        if (t >= off) x += sd[t-off];
        __syncthreads();
        sd[t] = x; __syncthreads();
    }
    if (t < nb) bsum[t] = (t == 0) ? 0 : sd[t-1];
    if (t == 0) seg_start[NSEG] = NE;
}

__global__ void scan3_k(const int* __restrict__ counts, const int* __restrict__ bsum,
                        int* __restrict__ seg_start){
    __shared__ int sd[256];
    int t = threadIdx.x;
    int base = blockIdx.x*1024 + t*4;
    int v[4]; int s = 0;
#pragma unroll
    for (int i = 0; i < 4; i++){ int idx = base + i; v[i] = (idx < NSEG) ? counts[idx] : 0; s += v[i]; }
    sd[t] = s; __syncthreads();
    for (int off = 1; off < 256; off <<= 1){
        int x = sd[t];
        if (t >= off) x += sd[t-off];
        __syncthreads();
        sd[t] = x; __syncthreads();
    }
    int excl = sd[t] - s + bsum[blockIdx.x];
#pragma unroll
    for (int i = 0; i < 4; i++){
        int idx = base + i;
        if (idx < NSEG){ seg_start[idx] = excl; excl += v[i]; }
    }
}

__global__ void scatter_k(const int* __restrict__ src, const int* __restrict__ dst,
                          const int* __restrict__ rel, const int* __restrict__ seg_start,
                          int* __restrict__ cursor, int* __restrict__ src_sorted){
    int e = blockIdx.x*256 + threadIdx.x;
    if (e < NE){
        int s = dst[e]*NR + rel[e];
        int pos = seg_start[s] + atomicAdd(&cursor[s], 1);
        src_sorted[pos] = src[e];
    }
}

// ---------------- layer 0: segment sum d=21, Kp=192 (147 upd | 21 self | 24 pad) ----------------

__global__ void segsum21b_k(const float* __restrict__ x0,
                            const int* __restrict__ seg_start, const int* __restrict__ src_sorted,
                            ushortT* __restrict__ Acat){
    int n = blockIdx.x;
    int t = threadIdx.x;   // 64
    ushortT* arow = Acat + (long)n*192;
    if (t < DIN){
        int sb = n*NR;
        int e0 = seg_start[sb];
#pragma unroll
        for (int r = 0; r < NR; r++){
            int e1 = seg_start[sb + r + 1];
            float a = 0.f;
            for (int e = e0; e < e1; e++) a += x0[(long)src_sorted[e]*DIN + t];
            e0 = e1;
            arow[r*DIN + t] = f2bf(a);
        }
        arow[7*DIN + t] = f2bf(x0[(long)n*DIN + t]);
    }
    if (t >= 40) arow[168 + (t - 40)] = 0;   // zero pad cols 168..191
}

// ---------------- segsum body (layers 1,2): one WAVE per node → Acat[*,3584] ----------------

__device__ inline void segsum_body(const ushortT* __restrict__ hbf,
                                   const int* __restrict__ seg_start,
                                   const int* __restrict__ src_sorted,
                                   ushortT* __restrict__ Acat,
                                   int wid, int c0, int lane){
    const int n = c0 + wid;
    const int co = lane*8;

    int sb[8];
#pragma unroll
    for (int i = 0; i < 8; i++) sb[i] = seg_start[n*NR + i];

    ushortT* arow = Acat + (long)wid*KSEG + co;
#pragma unroll
    for (int r = 0; r < NR; r++){
        float a[8];
#pragma unroll
        for (int j = 0; j < 8; j++) a[j] = 0.f;
        int e = sb[r], e1 = sb[r+1];
        for (; e + 3 < e1; e += 4){
            u16x8 v0 = *reinterpret_cast<const u16x8*>(hbf + (long)src_sorted[e  ]*DH + co);
            u16x8 v1 = *reinterpret_cast<const u16x8*>(hbf + (long)src_sorted[e+1]*DH + co);
            u16x8 v2 = *reinterpret_cast<const u16x8*>(hbf + (long)src_sorted[e+2]*DH + co);
            u16x8 v3 = *reinterpret_cast<const u16x8*>(hbf + (long)src_sorted[e+3]*DH + co);
#pragma unroll
            for (int j = 0; j < 8; j++)
                a[j] += (bf2f((ushortT)v0[j]) + bf2f((ushortT)v1[j]))
                      + (bf2f((ushortT)v2[j]) + bf2f((ushortT)v3[j]));
        }
        for (; e < e1; e++){
            u16x8 v = *reinterpret_cast<const u16x8*>(hbf + (long)src_sorted[e]*DH + co);
#pragma unroll
            for (int j = 0; j < 8; j++) a[j] += bf2f((ushortT)v[j]);
        }
        u16x8 o;
#pragma unroll
        for (int j = 0; j < 8; j++) o[j] = f2bf(a[j]);
        *reinterpret_cast<u16x8*>(arow + r*DH) = o;
    }
}

__global__ __launch_bounds__(256)
void segsum_wave_k(const ushortT* __restrict__ hbf,
                   const int* __restrict__ seg_start, const int* __restrict__ src_sorted,
                   ushortT* __restrict__ Acat, int c0, int cn){
    const int lane = threadIdx.x & 63;
    const int gwave = (blockIdx.x*256 + threadIdx.x) >> 6;
    const int nwaves = (gridDim.x*256) >> 6;
    for (int wid = gwave; wid < cn; wid += nwaves)
        segsum_body(hbf, seg_start, src_sorted, Acat, wid, c0, lane);
}

// ---------------- weight concat + bf16 convert: Wcat[512][Kp] ----------------

__global__ void convw_k(const float* __restrict__ lw, const float* __restrict__ sw,
                        int d, int Kp, ushortT* __restrict__ Wc){
    int i = blockIdx.x*256 + threadIdx.x;
    if (i < DH*Kp){
        int n = i / Kp, k = i % Kp;
        float v;
        if (k < 7*d)      v = lw[(long)n*7*d + k];
        else if (k < 8*d) v = sw[(long)n*d + (k - 7*d)];
        else              v = 0.f;
        Wc[i] = f2bf(v);
    }
}

// ---------------- dual-role: MFMA GEMM (128x128) + GRID-STRIDING segsum riders -------------
// GEMM blocks [0,gemmBlocks): exact R12 config (T2 swizzle both sides = zero bank conflicts,
// 4 waves of 64x64, 3-deep pipeline, counted vmcnt(4), raw barrier, bijective XCD swizzle,
// bf16 C + fused col-stats).
// Blocks >= gemmBlocks: segsum for the NEXT chunk, GRID-STRIDE over nodes (<= MAXRIDER
// blocks) so riders co-reside with GEMM blocks instead of serializing as a tail (R12 bug).

__global__ __launch_bounds__(256)
void gemm_seg_k(int gemmBlocks,
                const ushortT* __restrict__ A, int lda, int ntA,
                const ushortT* __restrict__ hbase, int M,
                const ushortT* __restrict__ W, int ldw,
                const float* __restrict__ b1, const float* __restrict__ b2,
                ushortT* __restrict__ C, int nt, float* __restrict__ sums,
                const ushortT* __restrict__ hbf,
                const int* __restrict__ seg_start, const int* __restrict__ src_sorted,
                ushortT* __restrict__ Acat2, int nc0, int ncn){
    __shared__ ushortT As[3][128*BK];   // 24 KB
    __shared__ ushortT Bs[3][128*BK];   // 24 KB
    const int t = threadIdx.x;

    if ((int)blockIdx.x >= gemmBlocks){
        const int lane   = t & 63;
        const int rwave  = ((int)blockIdx.x - gemmBlocks)*4 + (t >> 6);
        const int nwaves = ((int)gridDim.x - gemmBlocks)*4;
        for (int wid = rwave; wid < ncn; wid += nwaves)
            segsum_body(hbf, seg_start, src_sorted, Acat2, wid, nc0, lane);
        return;
    }

    // bijective XCD swizzle (m204) over gemmBlocks; panel = l>>2, col-tile = l&3
    const int nwg = gemmBlocks;
    int q = nwg >> 3, rmd = nwg & 7;
    int xcd = blockIdx.x & 7, slot = blockIdx.x >> 3;
    int l = xcd*q + min(xcd, rmd) + slot;
    const int bm = (l >> 2)*128;
    const int bn = (l & 3)*128;

    const int w    = t >> 6;
    const int lane = t & 63;

    int f0 = w*128 + lane, f1 = f0 + 64;
    // T2: swizzled k-chunk for the global source of LDS unit f
    const int ac0 = (((f0 & 3) ^ ((f0 >> 3) & 3)))*8;
    const int ac1 = (((f1 & 3) ^ ((f1 >> 3) & 3)))*8;
    const int ar0 = min(bm + (f0 >> 2), M-1);
    const int ar1 = min(bm + (f1 >> 2), M-1);
    const int br0 = bn + (f0 >> 2), br1 = bn + (f1 >> 2);
    const int d0 = (w*128 +  0)*8;
    const int d1 = (w*128 + 64)*8;

    f32x4 acc[4][4];
#pragma unroll
    for (int m = 0; m < 4; m++)
#pragma unroll
        for (int n = 0; n < 4; n++) acc[m][n] = (f32x4){0.f,0.f,0.f,0.f};

    const int wm = w >> 1, wn = w & 1;
    const int r = lane & 15, hi = lane >> 4;
    const int xr = (r >> 1) & 3;            // T2 read-side XOR
    const int ko = (hi ^ xr)*8;

    auto stage = [&](int kt, int b){
        const ushortT* p0;
        const ushortT* p1;
        if (kt < ntA){
            p0 = A + (long)ar0*lda + kt*BK + ac0;
            p1 = A + (long)ar1*lda + kt*BK + ac1;
        } else {
            int k0 = (kt - ntA)*BK;
            p0 = hbase + (long)ar0*DH + k0 + ac0;
            p1 = hbase + (long)ar1*DH + k0 + ac1;
        }
        load_lds16(p0, &As[b][d0]);
        load_lds16(p1, &As[b][d1]);
        load_lds16(W + (long)br0*ldw + kt*BK + ac0, &Bs[b][d0]);
        load_lds16(W + (long)br1*ldw + kt*BK + ac1, &Bs[b][d1]);
    };

    stage(0, 0);
    if (nt > 1) stage(1, 1);

    for (int kt = 0; kt < nt; ++kt){
        if (kt + 1 < nt) asm volatile("s_waitcnt vmcnt(4)" ::: "memory");
        else             asm volatile("s_waitcnt vmcnt(0)" ::: "memory");
        __builtin_amdgcn_s_barrier();
        __builtin_amdgcn_sched_barrier(0);
        if (kt + 2 < nt) stage(kt + 2, (kt + 2) % 3);
        const int buf = kt % 3;
        bf16x8 af[4], bfr[4];
#pragma unroll
        for (int m = 0; m < 4; m++)
            af[m] = *reinterpret_cast<const bf16x8*>(&As[buf][(wm*64 + m*16 + r)*BK + ko]);
#pragma unroll
        for (int n = 0; n < 4; n++)
            bfr[n] = *reinterpret_cast<const bf16x8*>(&Bs[buf][(wn*64 + n*16 + r)*BK + ko]);
#pragma unroll
        for (int m = 0; m < 4; m++)
#pragma unroll
            for (int n = 0; n < 4; n++)
                acc[m][n] = __builtin_amdgcn_mfma_f32_16x16x32_bf16(af[m], bfr[n], acc[m][n], 0, 0, 0);
    }

    // epilogue: bias + bf16 store + fused column stats (on rounded values)
#pragma unroll
    for (int n = 0; n < 4; n++){
        int col = bn + wn*64 + n*16 + r;
        float bb = b1[col] + b2[col];
        float s = 0.f, s2 = 0.f;
#pragma unroll
        for (int m = 0; m < 4; m++){
            int row = bm + wm*64 + m*16 + hi*4;
#pragma unroll
            for (int q2 = 0; q2 < 4; q2++){
                if (row + q2 < M){
                    ushortT u = f2bf(acc[m][n][q2] + bb);
                    C[(long)(row + q2)*DH + col] = u;
                    float vr = bf2f(u);
                    s += vr; s2 = fmaf(vr, vr, s2);
                }
            }
        }
        s  += __shfl_xor(s, 16);  s  += __shfl_xor(s, 32);
        s2 += __shfl_xor(s2, 16); s2 += __shfl_xor(s2, 32);
        if (hi == 0){
            atomicAdd(&sums[col], s);
            atomicAdd(&sums[DH + col], s2);
        }
    }
}

// ---------------- BatchNorm passes (bf16 buffer) ----------------

__global__ void finalize_k(const float* __restrict__ sums, const float* __restrict__ g,
                           const float* __restrict__ b, float* __restrict__ ac){
    int c = blockIdx.x*256 + threadIdx.x;
    if (c < DH){
        float mu  = sums[c] * (1.f/NN);
        float var = sums[DH + c] * (1.f/NN) - mu*mu;
        var = fmaxf(var, 0.f);
        float a = g[c] * rsqrtf(var + EPSB);
        ac[c]      = a;
        ac[DH + c] = fmaf(-mu, a, b[c]);
    }
}

__global__ void bnrelu_k(ushortT* __restrict__ buf, int M, const float* __restrict__ ac,
                         float* __restrict__ sums2){
    int col = blockIdx.x*256 + threadIdx.x;
    int r0 = blockIdx.y*128;
    int r1 = min(r0 + 128, M);
    float a = ac[col], c = ac[DH + col];
    float s = 0.f, s2 = 0.f;
    for (int r = r0; r < r1; r++){
        long idx = (long)r*DH + col;
        float y = fmaxf(fmaf(a, bf2f(buf[idx]), c), 0.f);
        ushortT u = f2bf(y);
        buf[idx] = u;
        float yr = bf2f(u);
        s += yr; s2 = fmaf(yr, yr, s2);
    }
    atomicAdd(&sums2[col], s);
    atomicAdd(&sums2[DH + col], s2);
}

__global__ void bn2write_k(const ushortT* __restrict__ buf, const float* __restrict__ ac,
                           float* __restrict__ out, ushortT* __restrict__ hbf, int layer){
    long i = (long)blockIdx.x*256 + threadIdx.x;
    if (i < (long)NN*DH){
        int r = (int)(i >> 9);
        int c = (int)(i & 511);
        float h = fmaf(ac[c], bf2f(buf[i]), ac[DH + c]);
        out[(long)r*(3*DH) + layer*DH + c] = h;
        hbf[i] = f2bf(h);
    }
}

// ---------------- driver ----------------

extern "C" void kernel_launch(void* const* d_in, const int* in_sizes, int n_in,
                              void* d_out, int out_size, void* d_ws, size_t ws_size,
                              hipStream_t stream){
    const float* x0  = (const float*)d_in[0];
    const int*   src = (const int*)d_in[1];
    const int*   dst = (const int*)d_in[2];
    const int*   rel = (const int*)d_in[3];
    const float* lin_w[3]  = {(const float*)d_in[4],  (const float*)d_in[12], (const float*)d_in[20]};
    const float* self_w[3] = {(const float*)d_in[5],  (const float*)d_in[13], (const float*)d_in[21]};
    const float* lin_b[3]  = {(const float*)d_in[6],  (const float*)d_in[14], (const float*)d_in[22]};
    const float* self_b[3] = {(const float*)d_in[7],  (const float*)d_in[15], (const float*)d_in[23]};
    const float* bn1_g[3]  = {(const float*)d_in[8],  (const float*)d_in[16], (const float*)d_in[24]};
    const float* bn1_b[3]  = {(const float*)d_in[9],  (const float*)d_in[17], (const float*)d_in[25]};
    const float* bn2_g[3]  = {(const float*)d_in[10], (const float*)d_in[18], (const float*)d_in[26]};
    const float* bn2_b[3]  = {(const float*)d_in[11], (const float*)d_in[19], (const float*)d_in[27]};

    char* ws = (char*)d_ws;
    size_t off = 0;
    auto alloc = [&](size_t bytes)->char*{ char* p = ws + off; off = align256(off + bytes); return p; };

    int*     counts     = (int*)alloc((size_t)NSEG*4);
    int*     cursor     = (int*)alloc((size_t)NSEG*4);
    int*     seg_start  = (int*)alloc((size_t)(NSEG+1)*4);
    int*     bsum       = (int*)alloc(1024*4);
    int*     src_sorted = (int*)alloc((size_t)NE*4);
    float*   stats      = (float*)alloc((size_t)8*DH*4);
    float*   sums1 = stats;            float* sums2 = stats + 2*DH;
    float*   ac1   = stats + 4*DH;     float* ac2   = stats + 6*DH;
    ushortT* outbuf = (ushortT*)alloc((size_t)NN*DH*2);
    ushortT* hbf    = (ushortT*)alloc((size_t)NN*DH*2);
    ushortT* Wcat   = (ushortT*)alloc((size_t)DH*4096*2);
    ushortT* Acat0  = (ushortT*)alloc((size_t)NN*192*2);

    // two Acat buffers (bf16, chunk x 3584); chunk <= CHMAX for L3 residency.
    size_t remain = (ws_size > off) ? (ws_size - off) : 0;
    long max_nodes = (long)(remain / (2*(size_t)KSEG*2));
    int chunk = (int)((max_nodes > CHMAX) ? CHMAX : max_nodes);
    chunk &= ~127;
    if (chunk < 128) chunk = 128;
    ushortT* AcatA = (ushortT*)(ws + off);
    ushortT* AcatB = AcatA + (size_t)chunk*KSEG;
    ushortT* AcatBuf[2] = {AcatA, AcatB};

    // CSR build (graph is layer-invariant)
    hipMemsetAsync(counts, 0, (size_t)NSEG*4, stream);
    hipMemsetAsync(cursor, 0, (size_t)NSEG*4, stream);
    hist_k<<<(NE+255)/256, 256, 0, stream>>>(dst, rel, counts);
    int nb = (NSEG + 1023)/1024;
    scan1_k<<<nb, 256, 0, stream>>>(counts, bsum);
    scan2_k<<<1, 256, 0, stream>>>(bsum, nb, seg_start);
    scan3_k<<<nb, 256, 0, stream>>>(counts, bsum, seg_start);
    scatter_k<<<(NE+255)/256, 256, 0, stream>>>(src, dst, rel, seg_start, cursor, src_sorted);

    const int MB = (NN + 127)/128;   // 235 row panels
    const int nch = (NN + chunk - 1)/chunk;

    for (int layer = 0; layer < 3; layer++){
        int d  = (layer == 0) ? DIN : DH;
        int Kp = (layer == 0) ? 192 : 8*DH;
        convw_k<<<(DH*Kp + 255)/256, 256, 0, stream>>>(lin_w[layer], self_w[layer], d, Kp, Wcat);
        hipMemsetAsync(stats, 0, (size_t)4*DH*4, stream);   // sums1 + sums2

        if (layer == 0){
            segsum21b_k<<<NN, 64, 0, stream>>>(x0, seg_start, src_sorted, Acat0);
            gemm_seg_k<<<MB*4, 256, 0, stream>>>(
                MB*4, Acat0, 192, 6, Acat0, NN, Wcat, 192,
                lin_b[layer], self_b[layer], outbuf, 6, sums1,
                hbf, seg_start, src_sorted, (ushortT*)nullptr, 0, 0);
        } else {
            int cn0 = (NN < chunk) ? NN : chunk;
            int sg0 = (cn0 + 3)/4; if (sg0 > 2048) sg0 = 2048;
            segsum_wave_k<<<sg0, 256, 0, stream>>>(
                hbf, seg_start, src_sorted, AcatBuf[0], 0, cn0);
            for (int i = 0; i < nch; i++){
                int cc0 = i*chunk;
                int ccn = (NN - cc0 < chunk) ? (NN - cc0) : chunk;
                int gemmBlocks = ((ccn + 127)/128)*4;
                int segBlocks = 0, nc0 = 0, ncn = 0;
                ushortT* An = nullptr;
                if (i + 1 < nch){
                    nc0 = (i + 1)*chunk;
                    ncn = (NN - nc0 < chunk) ? (NN - nc0) : chunk;
                    segBlocks = (ncn + 3)/4;
                    if (segBlocks > MAXRIDER) segBlocks = MAXRIDER;
                    An = AcatBuf[(i + 1) & 1];
                }
                gemm_seg_k<<<gemmBlocks + segBlocks, 256, 0, stream>>>(
                    gemmBlocks, AcatBuf[i & 1], KSEG, 112, hbf + (long)cc0*DH, ccn,
                    Wcat, 4096, lin_b[layer], self_b[layer],
                    outbuf + (long)cc0*DH, 128, sums1,
                    hbf, seg_start, src_sorted, An, nc0, ncn);
            }
        }

        finalize_k<<<2, 256, 0, stream>>>(sums1, bn1_g[layer], bn1_b[layer], ac1);
        bnrelu_k<<<dim3(2, (NN+127)/128), 256, 0, stream>>>(outbuf, NN, ac1, sums2);
        finalize_k<<<2, 256, 0, stream>>>(sums2, bn2_g[layer], bn2_b[layer], ac2);
        bn2write_k<<<((long)NN*DH + 255)/256, 256, 0, stream>>>(outbuf, ac2, (float*)d_out, hbf, layer);
    }
}

// Round 15
// 948.721 us; speedup vs baseline: 1.1781x; 1.0384x over previous
//
#include <hip/hip_runtime.h>

#define NN   30000
#define NE   480000
#define NR   7
#define NSEG (NN*NR)
#define DH   512
#define DIN  21
#define EPSB 1e-5f
#define KSEG 3584          // 7*512 gathered columns (self handled from hbf)

typedef __attribute__((ext_vector_type(8))) short bf16x8;
typedef __attribute__((ext_vector_type(8))) unsigned short u16x8;
typedef __attribute__((ext_vector_type(4))) float f32x4;
typedef unsigned short ushortT;

static inline size_t align256(size_t x){ return (x + 255) & ~(size_t)255; }

__device__ inline float bf2f(ushortT u){
    unsigned int i = ((unsigned int)u) << 16; float f; __builtin_memcpy(&f, &i, 4); return f;
}
__device__ inline ushortT f2bf(float f){
    unsigned int i; __builtin_memcpy(&i, &f, 4);
    unsigned int r = i + 0x7FFFu + ((i >> 16) & 1u);
    return (ushortT)(r >> 16);
}

__device__ inline void load_lds16(const ushortT* g, ushortT* l){
    __builtin_amdgcn_global_load_lds((const __attribute__((address_space(1))) unsigned int*)g,
                                     (__attribute__((address_space(3))) unsigned int*)l,
                                     16, 0, 0);
}

// ---------------- CSR build (counting sort by seg = dst*7+rel) ----------------

__global__ void hist_k(const int* __restrict__ dst, const int* __restrict__ rel,
                       int* __restrict__ counts){
    int e = blockIdx.x*256 + threadIdx.x;
    if (e < NE) atomicAdd(&counts[dst[e]*NR + rel[e]], 1);
}

__global__ void scan1_k(const int* __restrict__ counts, int* __restrict__ bsum){
    __shared__ int sd[256];
    int t = threadIdx.x;
    int base = blockIdx.x*1024 + t*4;
    int s = 0;
#pragma unroll
    for (int i = 0; i < 4; i++){ int idx = base + i; if (idx < NSEG) s += counts[idx]; }
    sd[t] = s; __syncthreads();
    for (int off = 128; off > 0; off >>= 1){
        if (t < off) sd[t] += sd[t+off];
        __syncthreads();
    }
    if (t == 0) bsum[blockIdx.x] = sd[0];
}

__global__ void scan2_k(int* __restrict__ bsum, int nb, int* __restrict__ seg_start){
    __shared__ int sd[256];
    int t = threadIdx.x;
    int v = (t < nb) ? bsum[t] : 0;
    sd[t] = v; __syncthreads();
    for (int off = 1; off < 256; off <<= 1){
        int x = sd[t];
        if (t >= off) x += sd[t-off];
        __syncthreads();
        sd[t] = x; __syncthreads();
    }
    if (t < nb) bsum[t] = (t == 0) ? 0 : sd[t-1];
    if (t == 0) seg_start[NSEG] = NE;
}

__global__ void scan3_k(const int* __restrict__ counts, const int* __restrict__ bsum,
                        int* __restrict__ seg_start){
    __shared__ int sd[256];
    int t = threadIdx.x;
    int base = blockIdx.x*1024 + t*4;
    int v[4]; int s = 0;
#pragma unroll
    for (int i = 0; i < 4; i++){ int idx = base + i; v[i] = (idx < NSEG) ? counts[idx] : 0; s += v[i]; }
    sd[t] = s; __syncthreads();
    for (int off = 1; off < 256; off <<= 1){
        int x = sd[t];
        if (t >= off) x += sd[t-off];
        __syncthreads();
        sd[t] = x; __syncthreads();
    }
    int excl = sd[t] - s + bsum[blockIdx.x];
#pragma unroll
    for (int i = 0; i < 4; i++){
        int idx = base + i;
        if (idx < NSEG){ seg_start[idx] = excl; excl += v[i]; }
    }
}

__global__ void scatter_k(const int* __restrict__ src, const int* __restrict__ dst,
                          const int* __restrict__ rel, const int* __restrict__ seg_start,
                          int* __restrict__ cursor, int* __restrict__ src_sorted){
    int e = blockIdx.x*256 + threadIdx.x;
    if (e < NE){
        int s = dst[e]*NR + rel[e];
        int pos = seg_start[s] + atomicAdd(&cursor[s], 1);
        src_sorted[pos] = src[e];
    }
}

// ---------------- layer 0: segment sum d=21 → Acat0[*,256] (147 upd | 21 self | pad) --------

__global__ void segsum21b_k(const float* __restrict__ x0,
                            const int* __restrict__ seg_start, const int* __restrict__ src_sorted,
                            ushortT* __restrict__ Acat0){
    int n = blockIdx.x;
    int t = threadIdx.x;   // 64
    ushortT* arow = Acat0 + (long)n*256;
    if (t < DIN){
        int sb = n*NR;
        int e0 = seg_start[sb];
#pragma unroll
        for (int r = 0; r < NR; r++){
            int e1 = seg_start[sb + r + 1];
            float a = 0.f;
            for (int e = e0; e < e1; e++) a += x0[(long)src_sorted[e]*DIN + t];
            e0 = e1;
            arow[r*DIN + t] = f2bf(a);
        }
        arow[7*DIN + t] = f2bf(x0[(long)n*DIN + t]);
    }
    if (t >= 40) arow[168 + (t - 40)] = 0;   // 168..191
    arow[192 + t] = 0;                        // 192..255
}

// ---------------- segsum (layers 1,2): one WAVE per node → Acat[*,3584], grid-stride --------

__device__ inline void segsum_body(const ushortT* __restrict__ hbf,
                                   const int* __restrict__ seg_start,
                                   const int* __restrict__ src_sorted,
                                   ushortT* __restrict__ Acat,
                                   int wid, int c0, int lane){
    const int n = c0 + wid;
    const int co = lane*8;

    int sb[8];
#pragma unroll
    for (int i = 0; i < 8; i++) sb[i] = seg_start[n*NR + i];

    ushortT* arow = Acat + (long)wid*KSEG + co;
#pragma unroll
    for (int r = 0; r < NR; r++){
        float a[8];
#pragma unroll
        for (int j = 0; j < 8; j++) a[j] = 0.f;
        int e = sb[r], e1 = sb[r+1];
        for (; e + 3 < e1; e += 4){
            u16x8 v0 = *reinterpret_cast<const u16x8*>(hbf + (long)src_sorted[e  ]*DH + co);
            u16x8 v1 = *reinterpret_cast<const u16x8*>(hbf + (long)src_sorted[e+1]*DH + co);
            u16x8 v2 = *reinterpret_cast<const u16x8*>(hbf + (long)src_sorted[e+2]*DH + co);
            u16x8 v3 = *reinterpret_cast<const u16x8*>(hbf + (long)src_sorted[e+3]*DH + co);
#pragma unroll
            for (int j = 0; j < 8; j++)
                a[j] += (bf2f((ushortT)v0[j]) + bf2f((ushortT)v1[j]))
                      + (bf2f((ushortT)v2[j]) + bf2f((ushortT)v3[j]));
        }
        for (; e < e1; e++){
            u16x8 v = *reinterpret_cast<const u16x8*>(hbf + (long)src_sorted[e]*DH + co);
#pragma unroll
            for (int j = 0; j < 8; j++) a[j] += bf2f((ushortT)v[j]);
        }
        u16x8 o;
#pragma unroll
        for (int j = 0; j < 8; j++) o[j] = f2bf(a[j]);
        *reinterpret_cast<u16x8*>(arow + r*DH) = o;
    }
}

__global__ __launch_bounds__(256)
void segsum_wave_k(const ushortT* __restrict__ hbf,
                   const int* __restrict__ seg_start, const int* __restrict__ src_sorted,
                   ushortT* __restrict__ Acat, int c0, int cn){
    const int lane = threadIdx.x & 63;
    const int gwave = (blockIdx.x*256 + threadIdx.x) >> 6;
    const int nwaves = (gridDim.x*256) >> 6;
    for (int wid = gwave; wid < cn; wid += nwaves)
        segsum_body(hbf, seg_start, src_sorted, Acat, wid, c0, lane);
}

// ---------------- weight concat + bf16 convert: Wcat[512][Kp] ----------------

__global__ void convw_k(const float* __restrict__ lw, const float* __restrict__ sw,
                        int d, int Kp, ushortT* __restrict__ Wc){
    int i = blockIdx.x*256 + threadIdx.x;
    if (i < DH*Kp){
        int n = i / Kp, k = i % Kp;
        float v;
        if (k < 7*d)      v = lw[(long)n*7*d + k];
        else if (k < 8*d) v = sw[(long)n*d + (k - 7*d)];
        else              v = 0.f;
        Wc[i] = f2bf(v);
    }
}

// ---------------- 8-phase 256x256 MFMA GEMM (T2+T3+T4+T5) ----------------
// 8 waves (2M x 4N of 128x64), BK=64, LDS = 2buf x (A 2half + B 2half) x [128][64] = 128 KB.
// Per tile: A frags register-hoisted in sub-phases 0-1 (A-LDS dies after ph1); each phase
// stages exactly one half-tile into a dead region; vmcnt(2) BEFORE the barrier at phases
// 3 and 7 guarantees cross-wave landing. Swizzle: chunk' = chunk ^ (row&7), both sides.
// C written fp32 directly to d_out slice (ldc), fused col-stats.

__global__ __launch_bounds__(512, 2)
void gemm8_k(const ushortT* __restrict__ A, int lda, int ntA,
             const ushortT* __restrict__ hbase, int M,
             const ushortT* __restrict__ W, int ldw,
             const float* __restrict__ b1, const float* __restrict__ b2,
             float* __restrict__ C, int ldc, int nt, float* __restrict__ sums){
    __shared__ ushortT As[2*2*128*64];   // [buf][half][row][64]
    __shared__ ushortT Bs[2*2*128*64];
    const int t = threadIdx.x;

    // bijective XCD swizzle; panel = l>>1, col-tile = l&1 (co-XCD A reuse)
    const int nwg = gridDim.x;
    int qq = nwg >> 3, rr = nwg & 7;
    int xcd = blockIdx.x & 7, slot = blockIdx.x >> 3;
    int l = xcd*qq + min(xcd, rr) + slot;
    const int bm = (l >> 1)*256;
    const int bn = (l & 1)*256;

    // staging constants: unit u0=t (rows 0-63 of half), u1=t+512 (rows 64-127)
    const int ur0 = t >> 3, ur1 = (t + 512) >> 3;
    const int sw0 = ((t & 7) ^ (ur0 & 7))*8;
    const int sw1 = ((t & 7) ^ (ur1 & 7))*8;
    const int a00 = min(bm + ur0, M-1),       a01 = min(bm + ur1, M-1);
    const int a10 = min(bm + 128 + ur0, M-1), a11 = min(bm + 128 + ur1, M-1);
    const int b00 = bn + ur0,       b01 = bn + ur1;
    const int b10 = bn + 128 + ur0, b11 = bn + 128 + ur1;

    auto stageA = [&](int kt, int h, int buf){
        ushortT* d = &As[(buf*2 + h)*8192];
        int r0 = h ? a10 : a00, r1 = h ? a11 : a01;
        const ushortT* p0;
        const ushortT* p1;
        if (kt < ntA){
            p0 = A + (long)r0*lda + kt*64 + sw0;
            p1 = A + (long)r1*lda + kt*64 + sw1;
        } else {
            int k0 = (kt - ntA)*64;
            p0 = hbase + (long)r0*DH + k0 + sw0;
            p1 = hbase + (long)r1*DH + k0 + sw1;
        }
        load_lds16(p0, d + t*8);
        load_lds16(p1, d + (t + 512)*8);
    };
    auto stageB = [&](int kt, int h, int buf){
        ushortT* d = &Bs[(buf*2 + h)*8192];
        int r0 = h ? b10 : b00, r1 = h ? b11 : b01;
        load_lds16(W + (long)r0*ldw + kt*64 + sw0, d + t*8);
        load_lds16(W + (long)r1*ldw + kt*64 + sw1, d + (t + 512)*8);
    };

    // fragment constants
    const int w = t >> 6, lane = t & 63;
    const int wm = w >> 2, wn = w & 3;          // 2 x 4 wave grid, wave tile 128x64
    const int r = lane & 15, hi = lane >> 4;
    const int swzk0 = ((hi)     ^ (r & 7))*8;   // ks=0
    const int swzk1 = ((4 + hi) ^ (r & 7))*8;   // ks=1
    const int aBase = wm*8192 + r*64;
    const int bBase = (wn >> 1)*8192 + ((wn & 1)*64 + r)*64;

    f32x4 acc[8][4];
#pragma unroll
    for (int m = 0; m < 8; m++)
#pragma unroll
        for (int n = 0; n < 4; n++) acc[m][n] = (f32x4){0.f,0.f,0.f,0.f};

    // prologue: tile0 (A h0,h1 + B h0,h1) -> buf0 ; tile1 (A h0,h1) -> buf1
    stageA(0, 0, 0); stageA(0, 1, 0);
    stageB(0, 0, 0); stageB(0, 1, 0);
    stageA(1, 0, 1); stageA(1, 1, 1);
    asm volatile("s_waitcnt vmcnt(4)" ::: "memory");   // tile0 fully landed
    __builtin_amdgcn_s_barrier();

    for (int it = 0; it < nt; it += 2){
#pragma unroll
        for (int b = 0; b < 2; ++b){
            bf16x8 aK0[8], aK1[8];
            const int bufo = b*16384;
#pragma unroll
            for (int qp = 0; qp < 4; ++qp){
                const int np = qp >> 1;
                const int swzk = (qp & 1) ? swzk1 : swzk0;
                // ds reads for this phase
                bf16x8 bb0 = *reinterpret_cast<const bf16x8*>(&Bs[bufo + bBase + (np*2+0)*1024 + swzk]);
                bf16x8 bb1 = *reinterpret_cast<const bf16x8*>(&Bs[bufo + bBase + (np*2+1)*1024 + swzk]);
                if (qp == 0){
#pragma unroll
                    for (int m = 0; m < 8; m++)
                        aK0[m] = *reinterpret_cast<const bf16x8*>(&As[bufo + aBase + m*1024 + swzk0]);
                }
                if (qp == 1){
#pragma unroll
                    for (int m = 0; m < 8; m++)
                        aK1[m] = *reinterpret_cast<const bf16x8*>(&As[bufo + aBase + m*1024 + swzk1]);
                }
                // stage one half-tile into a dead region
                {
                    const int ph = b*4 + qp;
                    if (ph == 0)      stageB(min(it+1, nt-1), 0, 1);
                    else if (ph == 1) stageB(min(it+1, nt-1), 1, 1);
                    else if (ph == 2) stageA(min(it+2, nt-1), 0, 0);
                    else if (ph == 3) stageA(min(it+2, nt-1), 1, 0);
                    else if (ph == 4) stageB(min(it+2, nt-1), 0, 0);
                    else if (ph == 5) stageB(min(it+2, nt-1), 1, 0);
                    else if (ph == 6) stageA(min(it+3, nt-1), 0, 1);
                    else              stageA(min(it+3, nt-1), 1, 1);
                }
                __builtin_amdgcn_s_barrier();
                asm volatile("s_waitcnt lgkmcnt(0)" ::: "memory");
                __builtin_amdgcn_sched_barrier(0);
                __builtin_amdgcn_s_setprio(1);
#pragma unroll
                for (int m = 0; m < 8; m++){
                    const bf16x8 am = (qp & 1) ? aK1[m] : aK0[m];
                    acc[m][np*2+0] = __builtin_amdgcn_mfma_f32_16x16x32_bf16(am, bb0, acc[m][np*2+0], 0, 0, 0);
                    acc[m][np*2+1] = __builtin_amdgcn_mfma_f32_16x16x32_bf16(am, bb1, acc[m][np*2+1], 0, 0, 0);
                }
                __builtin_amdgcn_s_setprio(0);
                if (qp == 3) asm volatile("s_waitcnt vmcnt(2)" ::: "memory");  // cross-wave landing guard
                __builtin_amdgcn_s_barrier();
            }
        }
    }
    asm volatile("s_waitcnt vmcnt(0)" ::: "memory");

    // epilogue: bias + fp32 store + fused column stats
#pragma unroll
    for (int n = 0; n < 4; n++){
        int col = bn + wn*64 + n*16 + r;
        float bb = b1[col] + b2[col];
        float s = 0.f, s2 = 0.f;
#pragma unroll
        for (int m = 0; m < 8; m++){
            int row = bm + wm*128 + m*16 + hi*4;
#pragma unroll
            for (int j2 = 0; j2 < 4; j2++){
                if (row + j2 < M){
                    float v = acc[m][n][j2] + bb;
                    C[(long)(row + j2)*ldc + col] = v;
                    s += v; s2 = fmaf(v, v, s2);
                }
            }
        }
        s  += __shfl_xor(s, 16);  s  += __shfl_xor(s, 32);
        s2 += __shfl_xor(s2, 16); s2 += __shfl_xor(s2, 32);
        if (hi == 0){
            atomicAdd(&sums[col], s);
            atomicAdd(&sums[DH + col], s2);
        }
    }
}

// ---------------- BatchNorm passes (fp32 in d_out, in place) ----------------

__global__ void finalize_k(const float* __restrict__ sums, const float* __restrict__ g,
                           const float* __restrict__ b, float* __restrict__ ac){
    int c = blockIdx.x*256 + threadIdx.x;
    if (c < DH){
        float mu  = sums[c] * (1.f/NN);
        float var = sums[DH + c] * (1.f/NN) - mu*mu;
        var = fmaxf(var, 0.f);
        float a = g[c] * rsqrtf(var + EPSB);
        ac[c]      = a;
        ac[DH + c] = fmaf(-mu, a, b[c]);
    }
}

__global__ void bnrelu_k(float* __restrict__ o, int M, const float* __restrict__ ac,
                         float* __restrict__ sums2){
    int col = blockIdx.x*256 + threadIdx.x;
    int r0 = blockIdx.y*128;
    int r1 = min(r0 + 128, M);
    float a = ac[col], c = ac[DH + col];
    float s = 0.f, s2 = 0.f;
    for (int r = r0; r < r1; r++){
        long idx = (long)r*(3*DH) + col;
        float y = fmaxf(fmaf(a, o[idx], c), 0.f);
        o[idx] = y;
        s += y; s2 = fmaf(y, y, s2);
    }
    atomicAdd(&sums2[col], s);
    atomicAdd(&sums2[DH + col], s2);
}

__global__ void bn2write_k(float* __restrict__ o, const float* __restrict__ ac,
                           ushortT* __restrict__ hbf){
    long i = (long)blockIdx.x*256 + threadIdx.x;
    if (i < (long)NN*DH){
        int r = (int)(i >> 9);
        int c = (int)(i & 511);
        long idx = (long)r*(3*DH) + c;
        float h = fmaf(ac[c], o[idx], ac[DH + c]);
        o[idx] = h;
        hbf[i] = f2bf(h);
    }
}

// ---------------- driver ----------------

extern "C" void kernel_launch(void* const* d_in, const int* in_sizes, int n_in,
                              void* d_out, int out_size, void* d_ws, size_t ws_size,
                              hipStream_t stream){
    const float* x0  = (const float*)d_in[0];
    const int*   src = (const int*)d_in[1];
    const int*   dst = (const int*)d_in[2];
    const int*   rel = (const int*)d_in[3];
    const float* lin_w[3]  = {(const float*)d_in[4],  (const float*)d_in[12], (const float*)d_in[20]};
    const float* self_w[3] = {(const float*)d_in[5],  (const float*)d_in[13], (const float*)d_in[21]};
    const float* lin_b[3]  = {(const float*)d_in[6],  (const float*)d_in[14], (const float*)d_in[22]};
    const float* self_b[3] = {(const float*)d_in[7],  (const float*)d_in[15], (const float*)d_in[23]};
    const float* bn1_g[3]  = {(const float*)d_in[8],  (const float*)d_in[16], (const float*)d_in[24]};
    const float* bn1_b[3]  = {(const float*)d_in[9],  (const float*)d_in[17], (const float*)d_in[25]};
    const float* bn2_g[3]  = {(const float*)d_in[10], (const float*)d_in[18], (const float*)d_in[26]};
    const float* bn2_b[3]  = {(const float*)d_in[11], (const float*)d_in[19], (const float*)d_in[27]};

    char* ws = (char*)d_ws;
    size_t off = 0;
    auto alloc = [&](size_t bytes)->char*{ char* p = ws + off; off = align256(off + bytes); return p; };

    int*     seg_start  = (int*)alloc((size_t)(NSEG+1)*4);
    int*     bsum       = (int*)alloc(1024*4);
    int*     src_sorted = (int*)alloc((size_t)NE*4);
    float*   stats      = (float*)alloc((size_t)8*DH*4);
    float*   sums1 = stats;            float* sums2 = stats + 2*DH;
    float*   ac1   = stats + 4*DH;     float* ac2   = stats + 6*DH;
    ushortT* hbf    = (ushortT*)alloc((size_t)NN*DH*2);
    ushortT* Wcat   = (ushortT*)alloc((size_t)DH*4096*2);

    // Acat takes the remainder. counts/cursor (CSR) and Acat0 (layer 0) are aliased
    // into the Acat region — all dead before the first layer-1 segsum write (stream-serial).
    size_t remain = (ws_size > off) ? (ws_size - off) : 0;
    ushortT* Acat   = (ushortT*)(ws + off);
    int*     counts = (int*)Acat;
    int*     cursor = counts + NSEG;
    ushortT* Acat0  = (ushortT*)align256((size_t)(cursor + NSEG));

    long max_nodes = (long)(remain / ((size_t)KSEG*2));
    int chunk;
    if (max_nodes >= NN) chunk = NN;
    else { chunk = (int)(max_nodes & ~255L); if (chunk < 2560) chunk = 2560; }

    // CSR build (graph is layer-invariant)
    hipMemsetAsync(counts, 0, (size_t)NSEG*4, stream);
    hipMemsetAsync(cursor, 0, (size_t)NSEG*4, stream);
    hist_k<<<(NE+255)/256, 256, 0, stream>>>(dst, rel, counts);
    int nb = (NSEG + 1023)/1024;
    scan1_k<<<nb, 256, 0, stream>>>(counts, bsum);
    scan2_k<<<1, 256, 0, stream>>>(bsum, nb, seg_start);
    scan3_k<<<nb, 256, 0, stream>>>(counts, bsum, seg_start);
    scatter_k<<<(NE+255)/256, 256, 0, stream>>>(src, dst, rel, seg_start, cursor, src_sorted);

    float* dout = (float*)d_out;

    for (int layer = 0; layer < 3; layer++){
        int d  = (layer == 0) ? DIN : DH;
        int Kp = (layer == 0) ? 256 : 4096;
        convw_k<<<(DH*Kp + 255)/256, 256, 0, stream>>>(lin_w[layer], self_w[layer], d, Kp, Wcat);
        hipMemsetAsync(stats, 0, (size_t)4*DH*4, stream);   // sums1 + sums2

        if (layer == 0){
            segsum21b_k<<<NN, 64, 0, stream>>>(x0, seg_start, src_sorted, Acat0);
            gemm8_k<<<((NN + 255)/256)*2, 512, 0, stream>>>(
                Acat0, 256, 4, Acat0, NN, Wcat, 256,
                lin_b[layer], self_b[layer],
                dout + layer*DH, 3*DH, 4, sums1);
        } else {
            for (int c0 = 0; c0 < NN; c0 += chunk){
                int cn = (NN - c0 < chunk) ? (NN - c0) : chunk;
                int sgrid = (cn + 3)/4; if (sgrid > 2048) sgrid = 2048;
                segsum_wave_k<<<sgrid, 256, 0, stream>>>(
                    hbf, seg_start, src_sorted, Acat, c0, cn);
                gemm8_k<<<((cn + 255)/256)*2, 512, 0, stream>>>(
                    Acat, KSEG, 56, hbf + (long)c0*DH, cn, Wcat, 4096,
                    lin_b[layer], self_b[layer],
                    dout + (long)c0*(3*DH) + layer*DH, 3*DH, 64, sums1);
            }
        }

        finalize_k<<<2, 256, 0, stream>>>(sums1, bn1_g[layer], bn1_b[layer], ac1);
        bnrelu_k<<<dim3(2, (NN+127)/128), 256, 0, stream>>>(dout + layer*DH, NN, ac1, sums2);
        finalize_k<<<2, 256, 0, stream>>>(sums2, bn2_g[layer], bn2_b[layer], ac2);
        bn2write_k<<<((long)NN*DH + 255)/256, 256, 0, stream>>>(dout + layer*DH, ac2, hbf);
    }
}